// Round 8
// baseline (565.212 us; speedup 1.0000x reference)
//
#include <hip/hip_runtime.h>

typedef unsigned short u16;
typedef unsigned int   u32;
typedef __attribute__((ext_vector_type(8))) short s16x8;
typedef __attribute__((ext_vector_type(4))) float f32x4;
typedef __attribute__((ext_vector_type(4))) u32   u32x4;
typedef __attribute__((ext_vector_type(4))) u16   u16x4;

#define NPIX 16641   /* 129*129 */
#define HP   131     /* padded spatial dim */

// ---- workspace layout (bytes) ----
// U    : [4][131][131][128] bf16  @ 0          (17,572,864)
// S1   : [2][131][131][512] bf16  @ 17572864   (35,145,728)
// Wt1  : [9][256][128] bf16       @ 52718592   (589,824)
// Wt2  : [9][256][512] bf16       @ 53308416   (2,359,296)
// out2a: [2*16641][256] bf16      @ 55667712   (17,040,384)  split-K half 0 (pre-relu, +bias)
// out2b: [2*16641][256] bf16      @ 72708096   (17,040,384)  split-K half 1
// w3t  : [256][49] f32            @ 89748480   (50,176)
// P    : [2][49][16641] f32       @ 89798656   (6,523,272)
// total 96,321,928 B

__device__ __forceinline__ u16 f2bf(float f) {
    u32 b = __builtin_bit_cast(u32, f);
    return (u16)((b + 0x7fffu + ((b >> 16) & 1u)) >> 16);
}
__device__ __forceinline__ float bf2f(u16 u) {
    return __builtin_bit_cast(float, ((u32)u) << 16);
}

// async global->LDS, 16B per lane; LDS dest wave-uniform base, lane l -> +16*l
__device__ __forceinline__ void async_cp16(const void* g, void* l) {
    __builtin_amdgcn_global_load_lds(
        (const __attribute__((address_space(1))) u32*)g,
        (__attribute__((address_space(3))) u32*)l, 16, 0, 0);
}

// zero only the 1-pixel pad ring of U (4 imgs, C=128) and S1 (2 imgs, C=512).
__global__ __launch_bounds__(256) void zero_border(u16* __restrict__ U,
                                                   u16* __restrict__ S1) {
    const int plane = blockIdx.y;           // 0..3: U, 4..5: S1
    const bool isU = plane < 4;
    const int C = isU ? 128 : 512;
    const int cpp = C / 8;
    int e = blockIdx.x * 256 + threadIdx.x;
    if (e >= 520 * cpp) return;
    int pix = e / cpp, ch = e - pix * cpp;
    int r, c;
    if (pix < 131)      { r = 0;   c = pix; }
    else if (pix < 262) { r = 130; c = pix - 131; }
    else { int j = pix - 262; r = 1 + (j >> 1); c = (j & 1) ? 130 : 0; }
    int img = isU ? plane : (plane - 4);
    u16* base = (isU ? U : S1) + ((long)(img * HP + r) * HP + c) * C + ch * 8;
    u32x4 z = {0u, 0u, 0u, 0u};
    *(u32x4*)base = z;
}

// transform weights: Wt[tap][co][ci] (bf16), w3t[c][t] (f32)
__global__ __launch_bounds__(256) void prep_weights(
        const float* __restrict__ wr, const float* __restrict__ w2,
        const float* __restrict__ w3,
        u16* __restrict__ Wt1, u16* __restrict__ Wt2, float* __restrict__ w3t) {
    int i = blockIdx.x * 256 + threadIdx.x;
    if (i < 294912) {
        int tap = i / 32768, r = i & 32767;
        int co = r >> 7, ci = r & 127;
        Wt1[i] = f2bf(wr[(co * 128 + ci) * 9 + tap]);
    } else if (i < 1474560) {
        int j = i - 294912;
        int tap = j / 131072, r = j & 131071;
        int co = r >> 9, ci = r & 511;
        Wt2[j] = f2bf(w2[(co * 512 + ci) * 9 + tap]);
    } else if (i < 1487104) {
        int j = i - 1474560;
        int c = j / 49, t = j - c * 49;
        w3t[j] = w3[t * 256 + c];
    }
}

// bilinear upsample 33x33 -> 129x129, write padded NHWC bf16
__global__ __launch_bounds__(256) void upsample(
        const float* __restrict__ cur, const float* __restrict__ key,
        u16* __restrict__ U) {
    __shared__ float rows[2][128][33];
    const int y = blockIdx.x;
    const int img = blockIdx.y;
    const int frame = img >> 1, bb = img & 1;
    const float* src = (frame ? key : cur) + (long)bb * 128 * 1089;
    const float scale = 33.0f / 129.0f;
    float syf = (y + 0.5f) * scale - 0.5f;
    int sy0 = (int)floorf(syf);
    float wy = syf - (float)sy0;
    int sy0c = sy0 < 0 ? 0 : sy0;
    int sy1c = (sy0 + 1 > 32) ? 32 : sy0 + 1;
    for (int e = threadIdx.x; e < 2 * 128 * 33; e += 256) {
        int rr = e / 4224;
        int rem = e - rr * 4224;
        int c = rem / 33, sx = rem - c * 33;
        rows[rr][c][sx] = src[((long)c * 33 + (rr ? sy1c : sy0c)) * 33 + sx];
    }
    __syncthreads();
    u16* dst = U + ((long)(img * HP + (y + 1)) * HP + 1) * 128;
    for (int e = threadIdx.x; e < 129 * 128; e += 256) {
        int x = e >> 7, c = e & 127;
        float sxf = (x + 0.5f) * scale - 0.5f;
        int sx0 = (int)floorf(sxf);
        float wx = sxf - (float)sx0;
        int sx0c = sx0 < 0 ? 0 : sx0;
        int sx1c = (sx0 + 1 > 32) ? 32 : sx0 + 1;
        float v0 = rows[0][c][sx0c] * (1.f - wx) + rows[0][c][sx1c] * wx;
        float v1 = rows[1][c][sx0c] * (1.f - wx) + rows[1][c][sx1c] * wx;
        dst[(long)x * 128 + c] = f2bf(v0 * (1.f - wy) + v1 * wy);
    }
}

// implicit-GEMM 3x3 conv via MFMA, 128x128 tile, BK=32 — r4 inner loop
// (verified conflicts = 0). SPLIT=2: split-K into separate bf16 partial
// buffers (bias in half 0, no relu); conv3 combines.
template<int CIN, int MODE, int NWORK, int SPLIT>
__global__ __launch_bounds__(256) void conv_mfma(
        const u16* __restrict__ In, const u16* __restrict__ Wt,
        const float* __restrict__ bias,
        u16* __restrict__ Out0, u16* __restrict__ Out1) {
    constexpr int KC  = CIN / 32;
    constexpr int NS  = 9 * KC;
    constexpr int NSH = NS / SPLIT;
    constexpr int PER = (NWORK + 7) / 8;
    __shared__ u16 As[2][128 * 32];
    __shared__ u16 Bs[2][128 * 32];

    const int id = blockIdx.x;
    const int work = (id & 7) * PER + (id >> 3);
    if (work >= NWORK) return;
    int w = work;
    const int m0 = (w & 1) * 128; w >>= 1;
    int half = 0;
    if (SPLIT == 2) { half = w & 1; w >>= 1; }
    const int xi  = w % 131;
    const int img = w / 131;
    const int p0  = xi * 128;

    const int t    = threadIdx.x;
    const int srow = t >> 2;
    const int scol = ((((t & 3) - (srow >> 1)) & 3) * 8);
    long ub[2];
    #pragma unroll
    for (int is = 0; is < 2; ++is) {
        int p = p0 + srow + is * 64; if (p > NPIX - 1) p = NPIX - 1;
        int y = p / 129, x = p - y * 129;
        ub[is] = ((long)(img * HP + y) * HP + x) * CIN + scol;
    }
    const long wb0 = (long)(m0 + srow) * CIN + scol;

    const int lane = t & 63;
    const int wave = t >> 6;
    const int wm = wave & 1, wn = wave >> 1;
    const int lm = lane & 15, lq = lane >> 4;
    const int koff = (((lq + (lm >> 1)) & 3) * 8);

    auto stage = [&](int s, int buf) {
        const int tap = s / KC;
        const int kc  = (s - tap * KC) * 32;
        const int ky = tap / 3, kx = tap - ky * 3;
        const long toff = (long)(ky * HP + kx) * CIN + kc;
        const u16* WtT = Wt + (long)tap * 256 * CIN + kc;
        char* Aw = (char*)&As[buf][0] + wave * 1024;
        char* Bw = (char*)&Bs[buf][0] + wave * 1024;
        async_cp16(WtT + wb0,             Aw);
        async_cp16(WtT + wb0 + 64L * CIN, Aw + 4096);
        async_cp16(In + ub[0] + toff,     Bw);
        async_cp16(In + ub[1] + toff,     Bw + 4096);
    };

    f32x4 acc[4][4];
    f32x4 zero = {0.f, 0.f, 0.f, 0.f};
    #pragma unroll
    for (int mt = 0; mt < 4; ++mt)
        #pragma unroll
        for (int nt = 0; nt < 4; ++nt) acc[mt][nt] = zero;

    const int s0 = half * NSH;
    stage(s0, 0);
    #pragma unroll 2
    for (int i = 0; i < NSH; ++i) {
        const int buf = i & 1;
        __syncthreads();
        if (i + 1 < NSH) stage(s0 + i + 1, buf ^ 1);
        s16x8 fa[4], fb[4];
        #pragma unroll
        for (int mt = 0; mt < 4; ++mt)
            fa[mt] = *(const s16x8*)&As[buf][(wm * 64 + mt * 16 + lm) * 32 + koff];
        #pragma unroll
        for (int nt = 0; nt < 4; ++nt)
            fb[nt] = *(const s16x8*)&Bs[buf][(wn * 64 + nt * 16 + lm) * 32 + koff];
        #pragma unroll
        for (int mt = 0; mt < 4; ++mt)
            #pragma unroll
            for (int nt = 0; nt < 4; ++nt)
                acc[mt][nt] = __builtin_amdgcn_mfma_f32_16x16x32_bf16(
                    fa[mt], fb[nt], acc[mt][nt], 0, 0, 0);
    }

    u16* OutBf = half ? Out1 : Out0;
    #pragma unroll
    for (int nt = 0; nt < 4; ++nt) {
        int p = p0 + wn * 64 + nt * 16 + lm;
        if (p > NPIX - 1) continue;
        long obase;
        if (MODE == 0) {
            int y = p / 129, x = p - y * 129;
            int bb = img & 1, frame = img >> 1;
            obase = ((long)(bb * HP + (y + 1)) * HP + (x + 1)) * 512 + frame * 256;
        } else {
            obase = ((long)img * NPIX + p) * 256;
        }
        #pragma unroll
        for (int mt = 0; mt < 4; ++mt) {
            int co = m0 + wm * 64 + mt * 16 + lq * 4;
            f32x4 bv = *(const f32x4*)(bias + co);
            if (MODE == 0) {
                float v0 = fmaxf(acc[mt][nt][0] + bv[0], 0.f);
                float v1 = fmaxf(acc[mt][nt][1] + bv[1], 0.f);
                float v2 = fmaxf(acc[mt][nt][2] + bv[2], 0.f);
                float v3 = fmaxf(acc[mt][nt][3] + bv[3], 0.f);
                u16x4 o = { f2bf(v0), f2bf(v1), f2bf(v2), f2bf(v3) };
                *(u16x4*)(OutBf + obase + co) = o;
            } else {
                float bs = half ? 0.f : 1.f;
                u16x4 o = { f2bf(acc[mt][nt][0] + bs * bv[0]),
                            f2bf(acc[mt][nt][1] + bs * bv[1]),
                            f2bf(acc[mt][nt][2] + bs * bv[2]),
                            f2bf(acc[mt][nt][3] + bs * bv[3]) };
                *(u16x4*)(OutBf + obase + co) = o;
            }
        }
    }
}

// combine split-K halves (add, relu) + 1x1 conv (256->49) + softmax.
// 4 threads/pixel (64 ch each), LDS reduce. Grid 521 x 256 (2 blocks/CU).
__global__ __launch_bounds__(256) void conv3_softmax(
        const u16* __restrict__ Xa, const u16* __restrict__ Xb,
        const float* __restrict__ W3t, const float* __restrict__ b3,
        float* __restrict__ P) {
    __shared__ float red[3][64][50];
    const int t = threadIdx.x;
    const int pl = t & 63, sub = t >> 6;
    const int idx = blockIdx.x * 64 + pl;
    const bool valid = idx < 2 * NPIX;
    float l[49];
    #pragma unroll
    for (int k = 0; k < 49; ++k) l[k] = 0.f;
    if (valid) {
        const s16x8* xra = (const s16x8*)(Xa + (long)idx * 256 + sub * 64);
        const s16x8* xrb = (const s16x8*)(Xb + (long)idx * 256 + sub * 64);
        #pragma unroll 1
        for (int cb = 0; cb < 8; ++cb) {
            s16x8 av = xra[cb];
            s16x8 bv = xrb[cb];
            #pragma unroll
            for (int j = 0; j < 8; ++j) {
                float xc = fmaxf(bf2f((u16)av[j]) + bf2f((u16)bv[j]), 0.f);
                const float* wrow = W3t + (sub * 64 + cb * 8 + j) * 49;
                #pragma unroll
                for (int k = 0; k < 49; ++k) l[k] = fmaf(wrow[k], xc, l[k]);
            }
        }
    }
    if (sub) {
        #pragma unroll
        for (int k = 0; k < 49; ++k) red[sub - 1][pl][k] = l[k];
    }
    __syncthreads();
    if (!sub && valid) {
        float m = 0.f;
        #pragma unroll
        for (int k = 0; k < 49; ++k) {
            l[k] = fmaxf(l[k] + red[0][pl][k] + red[1][pl][k] + red[2][pl][k]
                         + b3[k], 0.f);
            m = fmaxf(m, l[k]);
        }
        float ssum = 0.f;
        #pragma unroll
        for (int k = 0; k < 49; ++k) { l[k] = __expf(l[k] - m); ssum += l[k]; }
        float inv = 1.f / ssum;
        int bb = idx / NPIX, pix = idx - bb * NPIX;
        float* Pp = P + (long)bb * 49 * NPIX + pix;
        #pragma unroll
        for (int k = 0; k < 49; ++k) Pp[(long)k * NPIX] = l[k] * inv;
    }
}

// spatially-variant 7x7 conv v2: thread per pixel holds w[49] ONCE and loops
// 8 channel-groups (32 ch) internally — P logical traffic drops 64x -> 8x,
// and XCD swizzle (cg-range fastest within an XCD's contiguous work span)
// makes a tile's P lines L2-hit across its 8 cg-range blocks.
// Grid: 2 img x 66 px-tiles(256) x 8 cgr = 1056 blocks.
__global__ __launch_bounds__(256) void svconv(
        const float* __restrict__ F, const float* __restrict__ P,
        float* __restrict__ Out) {
    const int id = blockIdx.x;
    const int work = (id & 7) * 132 + (id >> 3);   // XCD swizzle, 1056 total
    const int cgr  = work & 7;                     // cg-range fastest
    const int tile = work >> 3;                    // 0..131
    const int ti   = tile % 66, img = tile / 66;
    const int pix  = ti * 256 + threadIdx.x;
    if (pix >= NPIX) return;
    const int y = pix / 129, x = pix - y * 129;

    float w[49];
    const float* Pp = P + (long)img * 49 * NPIX + pix;
    #pragma unroll
    for (int t = 0; t < 49; ++t) w[t] = Pp[(long)t * NPIX];

    #pragma unroll 1
    for (int cg = cgr * 8; cg < cgr * 8 + 8; ++cg) {
        const float* Fb = F + ((long)(img * 256 + cg * 4)) * NPIX;
        float acc0 = 0.f, acc1 = 0.f, acc2 = 0.f, acc3 = 0.f;
        #pragma unroll
        for (int ky = 0; ky < 7; ++ky) {
            unsigned uy = (unsigned)(y + ky - 3);
            #pragma unroll
            for (int kx = 0; kx < 7; ++kx) {
                unsigned ux = (unsigned)(x + kx - 3);
                if (uy < 129u && ux < 129u) {
                    long o = (long)uy * 129 + ux;
                    float wt = w[ky * 7 + kx];
                    acc0 = fmaf(wt, Fb[o], acc0);
                    acc1 = fmaf(wt, Fb[o + (long)NPIX], acc1);
                    acc2 = fmaf(wt, Fb[o + 2L * NPIX], acc2);
                    acc3 = fmaf(wt, Fb[o + 3L * NPIX], acc3);
                }
            }
        }
        float* Ob = Out + ((long)(img * 256 + cg * 4)) * NPIX + pix;
        Ob[0] = acc0;
        Ob[(long)NPIX] = acc1;
        Ob[2L * NPIX] = acc2;
        Ob[3L * NPIX] = acc3;
    }
}

extern "C" void kernel_launch(void* const* d_in, const int* in_sizes, int n_in,
                              void* d_out, int out_size, void* d_ws, size_t ws_size,
                              hipStream_t stream) {
    const float* cur      = (const float*)d_in[0];
    const float* key      = (const float*)d_in[1];
    const float* Fhigh    = (const float*)d_in[2];
    const float* w_reduce = (const float*)d_in[3];
    const float* b_reduce = (const float*)d_in[4];
    const float* w_conv2  = (const float*)d_in[5];
    const float* b_conv2  = (const float*)d_in[6];
    const float* w_conv3  = (const float*)d_in[7];
    const float* b_conv3  = (const float*)d_in[8];

    if (ws_size < 96321928UL) return;

    char* ws = (char*)d_ws;
    u16*   U     = (u16*)(ws + 0);
    u16*   S1    = (u16*)(ws + 17572864);
    u16*   Wt1   = (u16*)(ws + 52718592);
    u16*   Wt2   = (u16*)(ws + 53308416);
    u16*   out2a = (u16*)(ws + 55667712);
    u16*   out2b = (u16*)(ws + 72708096);
    float* w3t   = (float*)(ws + 89748480);
    float* P     = (float*)(ws + 89798656);

    zero_border<<<dim3(130, 6), 256, 0, stream>>>(U, S1);
    prep_weights<<<5809, 256, 0, stream>>>(w_reduce, w_conv2, w_conv3, Wt1, Wt2, w3t);
    upsample<<<dim3(129, 4), 256, 0, stream>>>(cur, key, U);
    conv_mfma<128, 0, 1048, 1><<<1048, 256, 0, stream>>>(U, Wt1, b_reduce, S1, S1);
    conv_mfma<512, 1, 1048, 2><<<1048, 256, 0, stream>>>(S1, Wt2, b_conv2, out2a, out2b);
    conv3_softmax<<<521, 256, 0, stream>>>(out2a, out2b, w3t, b_conv3, P);
    svconv<<<1056, 256, 0, stream>>>(Fhigh, P, (float*)d_out);
}

// Round 9
// 492.932 us; speedup vs baseline: 1.1466x; 1.1466x over previous
//
#include <hip/hip_runtime.h>

typedef unsigned short u16;
typedef unsigned int   u32;
typedef __attribute__((ext_vector_type(8))) short s16x8;
typedef __attribute__((ext_vector_type(4))) float f32x4;
typedef __attribute__((ext_vector_type(4), aligned(4))) float f32x4u;  // 4B-aligned vec load
typedef __attribute__((ext_vector_type(4))) u32   u32x4;
typedef __attribute__((ext_vector_type(4))) u16   u16x4;

#define NPIX 16641   /* 129*129 */
#define HP   131     /* padded spatial dim (convs) */
#define FPH  135     /* svconv padded F: height */
#define FPW  136     /* svconv padded F: row stride */
#define FPC  18360   /* FPH*FPW floats per channel */

// ---- workspace layout (bytes) ----
// region A (two lifetimes):
//   phase 1: U [4][131][131][128] bf16 @ 0 (17.6M), S1 [2][131][131][512] bf16 @ 17572864 (35.1M)
//   phase 2 (after conv2): Fpad [2][256][135][136] f32 @ 0 (37,601,280)
//                          P    [2][16641][52] f32     @ 37601280 (6,922,656)
// Wt1  : [9][256][128] bf16  @ 52718592   (589,824)
// Wt2  : [9][256][512] bf16  @ 53308416   (2,359,296)
// out2a: [2*16641][256] bf16 @ 55667712   (17,040,384)  split-K half 0 (pre-relu, +bias)
// out2b: [2*16641][256] bf16 @ 72708096   (17,040,384)  split-K half 1
// w3t  : [256][49] f32       @ 89748480   (50,176)
// total required: 89,798,656 B

__device__ __forceinline__ u16 f2bf(float f) {
    u32 b = __builtin_bit_cast(u32, f);
    return (u16)((b + 0x7fffu + ((b >> 16) & 1u)) >> 16);
}
__device__ __forceinline__ float bf2f(u16 u) {
    return __builtin_bit_cast(float, ((u32)u) << 16);
}

// async global->LDS, 16B per lane; LDS dest wave-uniform base, lane l -> +16*l
__device__ __forceinline__ void async_cp16(const void* g, void* l) {
    __builtin_amdgcn_global_load_lds(
        (const __attribute__((address_space(1))) u32*)g,
        (__attribute__((address_space(3))) u32*)l, 16, 0, 0);
}

// zero only the 1-pixel pad ring of U (4 imgs, C=128) and S1 (2 imgs, C=512).
__global__ __launch_bounds__(256) void zero_border(u16* __restrict__ U,
                                                   u16* __restrict__ S1) {
    const int plane = blockIdx.y;           // 0..3: U, 4..5: S1
    const bool isU = plane < 4;
    const int C = isU ? 128 : 512;
    const int cpp = C / 8;
    int e = blockIdx.x * 256 + threadIdx.x;
    if (e >= 520 * cpp) return;
    int pix = e / cpp, ch = e - pix * cpp;
    int r, c;
    if (pix < 131)      { r = 0;   c = pix; }
    else if (pix < 262) { r = 130; c = pix - 131; }
    else { int j = pix - 262; r = 1 + (j >> 1); c = (j & 1) ? 130 : 0; }
    int img = isU ? plane : (plane - 4);
    u16* base = (isU ? U : S1) + ((long)(img * HP + r) * HP + c) * C + ch * 8;
    u32x4 z = {0u, 0u, 0u, 0u};
    *(u32x4*)base = z;
}

// transform weights: Wt[tap][co][ci] (bf16), w3t[c][t] (f32)
__global__ __launch_bounds__(256) void prep_weights(
        const float* __restrict__ wr, const float* __restrict__ w2,
        const float* __restrict__ w3,
        u16* __restrict__ Wt1, u16* __restrict__ Wt2, float* __restrict__ w3t) {
    int i = blockIdx.x * 256 + threadIdx.x;
    if (i < 294912) {
        int tap = i / 32768, r = i & 32767;
        int co = r >> 7, ci = r & 127;
        Wt1[i] = f2bf(wr[(co * 128 + ci) * 9 + tap]);
    } else if (i < 1474560) {
        int j = i - 294912;
        int tap = j / 131072, r = j & 131071;
        int co = r >> 9, ci = r & 511;
        Wt2[j] = f2bf(w2[(co * 512 + ci) * 9 + tap]);
    } else if (i < 1487104) {
        int j = i - 1474560;
        int c = j / 49, t = j - c * 49;
        w3t[j] = w3[t * 256 + c];
    }
}

// bilinear upsample 33x33 -> 129x129, write padded NHWC bf16
__global__ __launch_bounds__(256) void upsample(
        const float* __restrict__ cur, const float* __restrict__ key,
        u16* __restrict__ U) {
    __shared__ float rows[2][128][33];
    const int y = blockIdx.x;
    const int img = blockIdx.y;
    const int frame = img >> 1, bb = img & 1;
    const float* src = (frame ? key : cur) + (long)bb * 128 * 1089;
    const float scale = 33.0f / 129.0f;
    float syf = (y + 0.5f) * scale - 0.5f;
    int sy0 = (int)floorf(syf);
    float wy = syf - (float)sy0;
    int sy0c = sy0 < 0 ? 0 : sy0;
    int sy1c = (sy0 + 1 > 32) ? 32 : sy0 + 1;
    for (int e = threadIdx.x; e < 2 * 128 * 33; e += 256) {
        int rr = e / 4224;
        int rem = e - rr * 4224;
        int c = rem / 33, sx = rem - c * 33;
        rows[rr][c][sx] = src[((long)c * 33 + (rr ? sy1c : sy0c)) * 33 + sx];
    }
    __syncthreads();
    u16* dst = U + ((long)(img * HP + (y + 1)) * HP + 1) * 128;
    for (int e = threadIdx.x; e < 129 * 128; e += 256) {
        int x = e >> 7, c = e & 127;
        float sxf = (x + 0.5f) * scale - 0.5f;
        int sx0 = (int)floorf(sxf);
        float wx = sxf - (float)sx0;
        int sx0c = sx0 < 0 ? 0 : sx0;
        int sx1c = (sx0 + 1 > 32) ? 32 : sx0 + 1;
        float v0 = rows[0][c][sx0c] * (1.f - wx) + rows[0][c][sx1c] * wx;
        float v1 = rows[1][c][sx0c] * (1.f - wx) + rows[1][c][sx1c] * wx;
        dst[(long)x * 128 + c] = f2bf(v0 * (1.f - wy) + v1 * wy);
    }
}

// implicit-GEMM 3x3 conv via MFMA, 128x128 tile, BK=32 — r4 inner loop
// (verified conflicts = 0). SPLIT=2: split-K into separate bf16 partial
// buffers (bias in half 0, no relu); conv3 combines.
template<int CIN, int MODE, int NWORK, int SPLIT>
__global__ __launch_bounds__(256) void conv_mfma(
        const u16* __restrict__ In, const u16* __restrict__ Wt,
        const float* __restrict__ bias,
        u16* __restrict__ Out0, u16* __restrict__ Out1) {
    constexpr int KC  = CIN / 32;
    constexpr int NS  = 9 * KC;
    constexpr int NSH = NS / SPLIT;
    constexpr int PER = (NWORK + 7) / 8;
    __shared__ u16 As[2][128 * 32];
    __shared__ u16 Bs[2][128 * 32];

    const int id = blockIdx.x;
    const int work = (id & 7) * PER + (id >> 3);
    if (work >= NWORK) return;
    int w = work;
    const int m0 = (w & 1) * 128; w >>= 1;
    int half = 0;
    if (SPLIT == 2) { half = w & 1; w >>= 1; }
    const int xi  = w % 131;
    const int img = w / 131;
    const int p0  = xi * 128;

    const int t    = threadIdx.x;
    const int srow = t >> 2;
    const int scol = ((((t & 3) - (srow >> 1)) & 3) * 8);
    long ub[2];
    #pragma unroll
    for (int is = 0; is < 2; ++is) {
        int p = p0 + srow + is * 64; if (p > NPIX - 1) p = NPIX - 1;
        int y = p / 129, x = p - y * 129;
        ub[is] = ((long)(img * HP + y) * HP + x) * CIN + scol;
    }
    const long wb0 = (long)(m0 + srow) * CIN + scol;

    const int lane = t & 63;
    const int wave = t >> 6;
    const int wm = wave & 1, wn = wave >> 1;
    const int lm = lane & 15, lq = lane >> 4;
    const int koff = (((lq + (lm >> 1)) & 3) * 8);

    auto stage = [&](int s, int buf) {
        const int tap = s / KC;
        const int kc  = (s - tap * KC) * 32;
        const int ky = tap / 3, kx = tap - ky * 3;
        const long toff = (long)(ky * HP + kx) * CIN + kc;
        const u16* WtT = Wt + (long)tap * 256 * CIN + kc;
        char* Aw = (char*)&As[buf][0] + wave * 1024;
        char* Bw = (char*)&Bs[buf][0] + wave * 1024;
        async_cp16(WtT + wb0,             Aw);
        async_cp16(WtT + wb0 + 64L * CIN, Aw + 4096);
        async_cp16(In + ub[0] + toff,     Bw);
        async_cp16(In + ub[1] + toff,     Bw + 4096);
    };

    f32x4 acc[4][4];
    f32x4 zero = {0.f, 0.f, 0.f, 0.f};
    #pragma unroll
    for (int mt = 0; mt < 4; ++mt)
        #pragma unroll
        for (int nt = 0; nt < 4; ++nt) acc[mt][nt] = zero;

    const int s0 = half * NSH;
    stage(s0, 0);
    #pragma unroll 2
    for (int i = 0; i < NSH; ++i) {
        const int buf = i & 1;
        __syncthreads();
        if (i + 1 < NSH) stage(s0 + i + 1, buf ^ 1);
        s16x8 fa[4], fb[4];
        #pragma unroll
        for (int mt = 0; mt < 4; ++mt)
            fa[mt] = *(const s16x8*)&As[buf][(wm * 64 + mt * 16 + lm) * 32 + koff];
        #pragma unroll
        for (int nt = 0; nt < 4; ++nt)
            fb[nt] = *(const s16x8*)&Bs[buf][(wn * 64 + nt * 16 + lm) * 32 + koff];
        #pragma unroll
        for (int mt = 0; mt < 4; ++mt)
            #pragma unroll
            for (int nt = 0; nt < 4; ++nt)
                acc[mt][nt] = __builtin_amdgcn_mfma_f32_16x16x32_bf16(
                    fa[mt], fb[nt], acc[mt][nt], 0, 0, 0);
    }

    u16* OutBf = half ? Out1 : Out0;
    #pragma unroll
    for (int nt = 0; nt < 4; ++nt) {
        int p = p0 + wn * 64 + nt * 16 + lm;
        if (p > NPIX - 1) continue;
        long obase;
        if (MODE == 0) {
            int y = p / 129, x = p - y * 129;
            int bb = img & 1, frame = img >> 1;
            obase = ((long)(bb * HP + (y + 1)) * HP + (x + 1)) * 512 + frame * 256;
        } else {
            obase = ((long)img * NPIX + p) * 256;
        }
        #pragma unroll
        for (int mt = 0; mt < 4; ++mt) {
            int co = m0 + wm * 64 + mt * 16 + lq * 4;
            f32x4 bv = *(const f32x4*)(bias + co);
            if (MODE == 0) {
                float v0 = fmaxf(acc[mt][nt][0] + bv[0], 0.f);
                float v1 = fmaxf(acc[mt][nt][1] + bv[1], 0.f);
                float v2 = fmaxf(acc[mt][nt][2] + bv[2], 0.f);
                float v3 = fmaxf(acc[mt][nt][3] + bv[3], 0.f);
                u16x4 o = { f2bf(v0), f2bf(v1), f2bf(v2), f2bf(v3) };
                *(u16x4*)(OutBf + obase + co) = o;
            } else {
                float bs = half ? 0.f : 1.f;
                u16x4 o = { f2bf(acc[mt][nt][0] + bs * bv[0]),
                            f2bf(acc[mt][nt][1] + bs * bv[1]),
                            f2bf(acc[mt][nt][2] + bs * bv[2]),
                            f2bf(acc[mt][nt][3] + bs * bv[3]) };
                *(u16x4*)(OutBf + obase + co) = o;
            }
        }
    }
}

// pad F (NCHW 129x129) into [2][256][135][136] f32 with 3-px zero halo.
// Thread per 4-float output chunk; fully overwrites the buffer every call.
__global__ __launch_bounds__(256) void fpad(
        const float* __restrict__ F, float* __restrict__ Fp) {
    int id = blockIdx.x * 256 + threadIdx.x;
    if (id >= 2 * 256 * FPH * (FPW / 4)) return;
    int ck = id % (FPW / 4);
    int r  = id / (FPW / 4);
    int yy = r % FPH;
    int ch = r / FPH;                       // 0..511 = img*256+c
    int y = yy - 3;
    f32x4 v;
    const float* Fr = F + ((long)ch * 129 + y) * 129;
    #pragma unroll
    for (int j = 0; j < 4; ++j) {
        int x = ck * 4 + j - 3;
        bool in = ((unsigned)x < 129u) && ((unsigned)y < 129u);
        v[j] = in ? Fr[x] : 0.f;
    }
    *(f32x4*)(Fp + (long)ch * FPC + yy * FPW + ck * 4) = v;
}

// combine split-K halves (add, relu) + 1x1 conv (256->49) + softmax.
// 4 threads/pixel (64 ch each), LDS reduce. P written [img][pix][52].
__global__ __launch_bounds__(256) void conv3_softmax(
        const u16* __restrict__ Xa, const u16* __restrict__ Xb,
        const float* __restrict__ W3t, const float* __restrict__ b3,
        float* __restrict__ P) {
    __shared__ float red[3][64][50];
    const int t = threadIdx.x;
    const int pl = t & 63, sub = t >> 6;
    const int idx = blockIdx.x * 64 + pl;
    const bool valid = idx < 2 * NPIX;
    float l[49];
    #pragma unroll
    for (int k = 0; k < 49; ++k) l[k] = 0.f;
    if (valid) {
        const s16x8* xra = (const s16x8*)(Xa + (long)idx * 256 + sub * 64);
        const s16x8* xrb = (const s16x8*)(Xb + (long)idx * 256 + sub * 64);
        #pragma unroll 1
        for (int cb = 0; cb < 8; ++cb) {
            s16x8 av = xra[cb];
            s16x8 bv = xrb[cb];
            #pragma unroll
            for (int j = 0; j < 8; ++j) {
                float xc = fmaxf(bf2f((u16)av[j]) + bf2f((u16)bv[j]), 0.f);
                const float* wrow = W3t + (sub * 64 + cb * 8 + j) * 49;
                #pragma unroll
                for (int k = 0; k < 49; ++k) l[k] = fmaf(wrow[k], xc, l[k]);
            }
        }
    }
    if (sub) {
        #pragma unroll
        for (int k = 0; k < 49; ++k) red[sub - 1][pl][k] = l[k];
    }
    __syncthreads();
    if (!sub && valid) {
        float m = 0.f;
        #pragma unroll
        for (int k = 0; k < 49; ++k) {
            l[k] = fmaxf(l[k] + red[0][pl][k] + red[1][pl][k] + red[2][pl][k]
                         + b3[k], 0.f);
            m = fmaxf(m, l[k]);
        }
        float ssum = 0.f;
        #pragma unroll
        for (int k = 0; k < 49; ++k) { l[k] = __expf(l[k] - m); ssum += l[k]; }
        float inv = 1.f / ssum;
        int bb = idx / NPIX, pix = idx - bb * NPIX;
        float* Pp = P + ((long)bb * NPIX + pix) * 52;
        #pragma unroll
        for (int k = 0; k < 49; ++k) Pp[k] = l[k] * inv;
    }
}

// spatially-variant 7x7 conv v3: padded F (no bounds checks), vectorized
// row loads (2x dwordx4 per row), w[49] via 13 aligned dwordx4 from
// P[img][pix][52]. One cg (4 ch) per thread for TLP (8448 blocks); XCD
// swizzle with cg fastest so the 64 blocks sharing a pixel tile hit the
// same P lines in their XCD's L2.
__global__ __launch_bounds__(256) void svconv(
        const float* __restrict__ Fp, const float* __restrict__ P,
        float* __restrict__ Out) {
    const int id = blockIdx.x;
    const int work = (id & 7) * 1056 + (id >> 3);  // 8448 total
    const int cg   = work & 63;                    // fastest within XCD span
    const int tile = work >> 6;                    // 0..131
    const int img  = tile / 66, ti = tile % 66;
    const int pix  = ti * 256 + threadIdx.x;
    if (pix >= NPIX) return;
    const int y = pix / 129, x = pix - y * 129;

    float w[52];
    const f32x4* Pp = (const f32x4*)(P + ((long)img * NPIX + pix) * 52);
    #pragma unroll
    for (int k = 0; k < 13; ++k) *(f32x4*)&w[k * 4] = Pp[k];

    const float* Fc0 = Fp + (long)(img * 256 + cg * 4) * FPC + (long)y * FPW + x;
    float acc[4];
    #pragma unroll
    for (int c4 = 0; c4 < 4; ++c4) {
        const float* Fc = Fc0 + c4 * FPC;
        float a = 0.f;
        #pragma unroll
        for (int ky = 0; ky < 7; ++ky) {
            const float* rp = Fc + ky * FPW;
            f32x4u v0 = *(const f32x4u*)rp;
            f32x4u v1 = *(const f32x4u*)(rp + 4);
            const float* wr = &w[ky * 7];
            a = fmaf(wr[0], v0[0], a);
            a = fmaf(wr[1], v0[1], a);
            a = fmaf(wr[2], v0[2], a);
            a = fmaf(wr[3], v0[3], a);
            a = fmaf(wr[4], v1[0], a);
            a = fmaf(wr[5], v1[1], a);
            a = fmaf(wr[6], v1[2], a);
        }
        acc[c4] = a;
    }
    float* Ob = Out + ((long)(img * 256 + cg * 4)) * NPIX + pix;
    Ob[0] = acc[0];
    Ob[(long)NPIX] = acc[1];
    Ob[2L * NPIX] = acc[2];
    Ob[3L * NPIX] = acc[3];
}

extern "C" void kernel_launch(void* const* d_in, const int* in_sizes, int n_in,
                              void* d_out, int out_size, void* d_ws, size_t ws_size,
                              hipStream_t stream) {
    const float* cur      = (const float*)d_in[0];
    const float* key      = (const float*)d_in[1];
    const float* Fhigh    = (const float*)d_in[2];
    const float* w_reduce = (const float*)d_in[3];
    const float* b_reduce = (const float*)d_in[4];
    const float* w_conv2  = (const float*)d_in[5];
    const float* b_conv2  = (const float*)d_in[6];
    const float* w_conv3  = (const float*)d_in[7];
    const float* b_conv3  = (const float*)d_in[8];

    if (ws_size < 89798656UL) return;

    char* ws = (char*)d_ws;
    // phase 1 (through conv2)
    u16*   U     = (u16*)(ws + 0);
    u16*   S1    = (u16*)(ws + 17572864);
    // phase 2 (after conv2; overlays U/S1 region)
    float* Fpad  = (float*)(ws + 0);           // 37,601,280 B
    float* P     = (float*)(ws + 37601280);    //  6,922,656 B
    u16*   Wt1   = (u16*)(ws + 52718592);
    u16*   Wt2   = (u16*)(ws + 53308416);
    u16*   out2a = (u16*)(ws + 55667712);
    u16*   out2b = (u16*)(ws + 72708096);
    float* w3t   = (float*)(ws + 89748480);

    zero_border<<<dim3(130, 6), 256, 0, stream>>>(U, S1);
    prep_weights<<<5809, 256, 0, stream>>>(w_reduce, w_conv2, w_conv3, Wt1, Wt2, w3t);
    upsample<<<dim3(129, 4), 256, 0, stream>>>(cur, key, U);
    conv_mfma<128, 0, 1048, 1><<<1048, 256, 0, stream>>>(U, Wt1, b_reduce, S1, S1);
    conv_mfma<512, 1, 1048, 2><<<1048, 256, 0, stream>>>(S1, Wt2, b_conv2, out2a, out2b);
    fpad<<<9180, 256, 0, stream>>>(Fhigh, Fpad);          // overlays U/S1 (dead)
    conv3_softmax<<<521, 256, 0, stream>>>(out2a, out2b, w3t, b_conv3, P);
    svconv<<<8448, 256, 0, stream>>>(Fpad, P, (float*)d_out);
}